// Round 4
// baseline (477186.816 us; speedup 1.0000x reference)
//
#include <hip/hip_runtime.h>

// PEPS 10x10 boundary-MPS contraction, D=8, Dc=64, 2 sweeps, fp32.
// Host-orchestrated graph of ~1490 small kernels. All shapes are static
// (data-independent), so the schedule is identical every call (graph-safe).
//
// Conventions (matching the JAX reference):
//   mps site  m: (d, p, r)          row-major
//   mpo site  w: (l, w, p, q)       row-major  (p = up/in, q = down/out)
//   result    A: (a, q, b)          row-major
//   left env  L: (d, l, a)          row-major
//   right env R: (r, w, b)          row-major
// QR: Q_k = orthonormalization (MGS2) of the first KK columns; R = Q_k^T A.
// Gauge-invariance of the final scalar makes the QR basis convention free.
// Sweep neighbor C-updates in the reference are dead code and are elided.

#define TINYF 1e-30f

__device__ __forceinline__ float wsum(float v){
  v += __shfl_xor(v, 1);  v += __shfl_xor(v, 2);  v += __shfl_xor(v, 4);
  v += __shfl_xor(v, 8);  v += __shfl_xor(v, 16); v += __shfl_xor(v, 32);
  return v;
}

__global__ void k_init(float* u){ u[0] = 1.0f; }

// Build all 100 MPO tensors: t = tensors[row,col,spin,:up,:dn,:lf,:rt] -> (l,w,p,q)
__global__ void k_mpo(const float* __restrict__ T, const int* __restrict__ spins,
                      float* __restrict__ mpo){
  int s = blockIdx.x; int row = s / 10, col = s % 10;
  int up = (row == 0) ? 1 : 8, dn = (row == 9) ? 1 : 8;
  int lf = (col == 0) ? 1 : 8, rt = (col == 9) ? 1 : 8;
  int spin = spins[s];
  const float* src = T + (size_t)(s * 2 + spin) * 4096; // strides: up=512, dn=64, lf=8, rt=1
  float* dst = mpo + (size_t)s * 4096;                  // (l, w, p, q) packed
  int n = lf * rt * up * dn;
  for (int i = threadIdx.x; i < n; i += blockDim.x){
    int q = i % dn, t1 = i / dn, p = t1 % up, t2 = t1 / up, w = t2 % rt, l = t2 / rt;
    dst[i] = src[p * 512 + q * 64 + l * 8 + w];
  }
}

// theta[k,q,r,w] = sum_{d,l,p} carry[k,d,l] m[d,p,r] w[l,w,p,q]
// out as matrix: out[(k*Qd+q)*(rm*Ww) + r*Ww + w_]
__global__ __launch_bounds__(256) void k_init_theta(
    const float* __restrict__ carry, const float* __restrict__ m,
    const float* __restrict__ w, float* __restrict__ out,
    int kdim, int dm, int lw, int P, int rm, int Ww, int Qd){
  int k = blockIdx.x;
  __shared__ float sC[512];    // (dm, lw)
  __shared__ float sT1[4096];  // (p*rm + r)*lw + l
  __shared__ float sW[4096];
  for (int i = threadIdx.x; i < dm * lw; i += blockDim.x) sC[i] = carry[(size_t)k * dm * lw + i];
  for (int i = threadIdx.x; i < lw * Ww * P * Qd; i += blockDim.x) sW[i] = w[i];
  __syncthreads();
  // stage 1: per-thread (p,r) pair, global operand hoisted per d
  for (int j = threadIdx.x; j < P * rm; j += blockDim.x){
    int r = j % rm, p = j / rm;
    float acc[8];
    #pragma unroll
    for (int l = 0; l < 8; ++l) acc[l] = 0.f;
    for (int d = 0; d < dm; ++d){
      float mv = m[((size_t)d * P + p) * rm + r];
      #pragma unroll
      for (int l = 0; l < 8; ++l) if (l < lw) acc[l] += mv * sC[d * lw + l];
    }
    float* dst = sT1 + (size_t)j * lw;
    for (int l = 0; l < lw; ++l) dst[l] = acc[l];
  }
  __syncthreads();
  int n2 = Qd * rm * Ww;
  int ldo = rm * Ww;
  for (int i = threadIdx.x; i < n2; i += blockDim.x){
    int w_ = i % Ww, t = i / Ww, r = t % rm, q = t / rm;
    float acc = 0.f;
    for (int l = 0; l < lw; ++l)
      for (int p = 0; p < P; ++p)
        acc += sT1[(p * rm + r) * lw + l] * sW[((l * Ww + w_) * P + p) * Qd + q];
    out[(size_t)(k * Qd + q) * ldo + r * Ww + w_] = acc;
  }
}

// Orthonormalize first KK columns of A (M rows), strided access, MGS2.
// A(row,col) at A[row*ars + col*acs]; Q(row,col) at Q[row*qrs + col*qcs].
// Register-resident: 16 waves; wave w owns columns {w+16k}; column spread
// across the wave's 64 lanes (row r = lane + 64t, t<8 -> 32 VGPRs/lane).
// Per pivot step only the 2KB pivot column goes through LDS (double-buffered),
// one __syncthreads per step. MGS2 = two identical passes.
__global__ __launch_bounds__(1024) void k_panel(
    const float* __restrict__ A, float* __restrict__ Q,
    int M, int KK, int ars, int acs, int qrs, int qcs){
  __shared__ float piv[2][512];   // pivot column, lane-major: [t*64 + lane]
  __shared__ float pnrm[2];       // pivot ||.||^2
  __shared__ float colnrm[64];    // final norms for store
  int wv = threadIdx.x >> 6, lane = threadIdx.x & 63;
  int T = (M + 63) >> 6;          // <= 8
  float creg[4][8];
  #pragma unroll
  for (int k = 0; k < 4; ++k)
    #pragma unroll
    for (int t = 0; t < 8; ++t) creg[k][t] = 0.f;
  // load owned columns (rows >= M stay 0)
  for (int k = 0; k < 4; ++k){
    int c = wv + (k << 4);
    if (c < KK){
      for (int t = 0; t < T; ++t){
        int r = lane + (t << 6);
        if (r < M) creg[k][t] = A[(size_t)r * ars + (size_t)c * acs];
      }
    }
  }
  if (KK == 1){
    if (wv == 0){
      float s = 0.f;
      for (int t = 0; t < T; ++t) s += creg[0][t] * creg[0][t];
      s = wsum(s);
      if (lane == 0) colnrm[0] = s;
    }
    __syncthreads();
  } else {
    for (int pass = 0; pass < 2; ++pass){
      if (wv == 0){           // publish column 0 into buffer 0
        float s = 0.f;
        for (int t = 0; t < T; ++t) s += creg[0][t] * creg[0][t];
        s = wsum(s);
        for (int t = 0; t < T; ++t) piv[0][(t << 6) + lane] = creg[0][t];
        if (lane == 0){ pnrm[0] = s; if (pass == 1) colnrm[0] = s; }
      }
      __syncthreads();
      for (int j = 0; j < KK - 1; ++j){
        int buf = j & 1;
        float pv[8];
        for (int t = 0; t < T; ++t) pv[t] = piv[buf][(t << 6) + lane];
        float invn = 1.0f / fmaxf(pnrm[buf], TINYF);
        #pragma unroll
        for (int k = 0; k < 4; ++k){
          int c = wv + (k << 4);
          if (c > j && c < KK){
            float d = 0.f;
            for (int t = 0; t < T; ++t) d += pv[t] * creg[k][t];
            d = wsum(d);
            float coef = d * invn;
            for (int t = 0; t < T; ++t) creg[k][t] -= coef * pv[t];
            if (c == j + 1){   // next pivot: publish updated column + norm
              float s = 0.f;
              for (int t = 0; t < T; ++t) s += creg[k][t] * creg[k][t];
              s = wsum(s);
              int nb = buf ^ 1;
              for (int t = 0; t < T; ++t) piv[nb][(t << 6) + lane] = creg[k][t];
              if (lane == 0){ pnrm[nb] = s; if (pass == 1) colnrm[j + 1] = s; }
            }
          }
        }
        __syncthreads();
      }
    }
  }
  // store Q = col * rsqrt(norm); colnrm visible via the last barrier
  for (int k = 0; k < 4; ++k){
    int c = wv + (k << 4);
    if (c < KK){
      float rs = rsqrtf(fmaxf(colnrm[c], TINYF));
      for (int t = 0; t < T; ++t){
        int r = lane + (t << 6);
        if (r < M) Q[(size_t)r * qrs + (size_t)c * qcs] = creg[k][t] * rs;
      }
    }
  }
}

// R[c][n] = sum_m Q[m*KK + c] * A[m*ars + n*acs]   (R: KK x N, row-major)
__global__ __launch_bounds__(256) void k_rmat(
    const float* __restrict__ Q, const float* __restrict__ A, float* __restrict__ R,
    int M, int KK, int N, int ars, int acs){
  int idx = blockIdx.x * blockDim.x + threadIdx.x;
  if (idx >= KK * N) return;
  int n = idx % N, c = idx / N;
  float acc = 0.f;
  for (int mm = 0; mm < M; ++mm)
    acc += Q[(size_t)mm * KK + c] * A[(size_t)mm * ars + (size_t)n * acs];
  R[idx] = acc;
}

// optimal[a,q,b] = sum m[d,p,r] L[d,l,a] w[l,w,p,q] R[r,w,b]; one WG per a.
__global__ __launch_bounds__(256) void k_optimal(
    const float* __restrict__ m, const float* __restrict__ L,
    const float* __restrict__ w, const float* __restrict__ Renv, float* __restrict__ out,
    int dm, int P, int rm, int lw, int aL, int Ww, int Qd, int bR){
  int a = blockIdx.x;
  __shared__ float sL[512];    // (dm, lw)
  __shared__ float sT1[4096];  // (p*rm + r)*lw + l
  __shared__ float sT2[4096];  // (r*Ww + w_)*Qd + q
  __shared__ float sW[4096];
  for (int i = threadIdx.x; i < dm * lw; i += blockDim.x){
    int d = i / lw, l = i % lw;
    sL[i] = L[((size_t)d * lw + l) * aL + a];
  }
  for (int i = threadIdx.x; i < lw * Ww * P * Qd; i += blockDim.x) sW[i] = w[i];
  __syncthreads();
  for (int j = threadIdx.x; j < P * rm; j += blockDim.x){
    int r = j % rm, p = j / rm;
    float acc[8];
    #pragma unroll
    for (int l = 0; l < 8; ++l) acc[l] = 0.f;
    for (int d = 0; d < dm; ++d){
      float mv = m[((size_t)d * P + p) * rm + r];
      #pragma unroll
      for (int l = 0; l < 8; ++l) if (l < lw) acc[l] += mv * sL[d * lw + l];
    }
    float* dst = sT1 + (size_t)j * lw;
    for (int l = 0; l < lw; ++l) dst[l] = acc[l];
  }
  __syncthreads();
  for (int i = threadIdx.x; i < rm * Ww * Qd; i += blockDim.x){
    int q = i % Qd, t = i / Qd, w_ = t % Ww, r = t / Ww;
    float acc = 0.f;
    for (int l = 0; l < lw; ++l)
      for (int p = 0; p < P; ++p)
        acc += sT1[(p * rm + r) * lw + l] * sW[((l * Ww + w_) * P + p) * Qd + q];
    sT2[i] = acc;
  }
  __syncthreads();
  int n3 = Qd * bR;
  for (int i = threadIdx.x; i < n3; i += blockDim.x){
    int b = i % bR, q = i / bR;
    float acc = 0.f;
    for (int r = 0; r < rm; ++r)
      for (int w_ = 0; w_ < Ww; ++w_)
        acc += sT2[(r * Ww + w_) * Qd + q] * Renv[((size_t)r * Ww + w_) * bR + b];
    out[((size_t)a * Qd + q) * bR + b] = acc;
  }
}

// Lnew[r,w,b] = sum m[d,p,r] L[d,l,a] w[l,w,p,q] A[a,q,b]; one WG per r.
__global__ __launch_bounds__(256) void k_lenv(
    const float* __restrict__ m, const float* __restrict__ L,
    const float* __restrict__ w, const float* __restrict__ A, float* __restrict__ out,
    int dm, int P, int rm, int lw, int aL, int Ww, int Qd, int KK){
  int r = blockIdx.x;
  __shared__ float sM[512];    // (dm, P)
  __shared__ float sT1[4096];  // (p*lw + l)*aL + a
  __shared__ float sT2[4096];  // (a*Ww + w_)*Qd + q
  __shared__ float sW[4096];
  for (int i = threadIdx.x; i < dm * P; i += blockDim.x){
    int d = i / P, p = i % P;
    sM[i] = m[((size_t)d * P + p) * rm + r];
  }
  for (int i = threadIdx.x; i < lw * Ww * P * Qd; i += blockDim.x) sW[i] = w[i];
  __syncthreads();
  for (int j = threadIdx.x; j < lw * aL; j += blockDim.x){
    int a = j % aL, l = j / aL;
    float acc[8];
    #pragma unroll
    for (int p = 0; p < 8; ++p) acc[p] = 0.f;
    for (int d = 0; d < dm; ++d){
      float Lv = L[((size_t)d * lw + l) * aL + a];
      #pragma unroll
      for (int p = 0; p < 8; ++p) if (p < P) acc[p] += sM[d * P + p] * Lv;
    }
    for (int p = 0; p < P; ++p) sT1[(size_t)p * lw * aL + j] = acc[p];
  }
  __syncthreads();
  for (int i = threadIdx.x; i < aL * Ww * Qd; i += blockDim.x){
    int q = i % Qd, t = i / Qd, w_ = t % Ww, a = t / Ww;
    float acc = 0.f;
    for (int l = 0; l < lw; ++l)
      for (int p = 0; p < P; ++p)
        acc += sT1[(p * lw + l) * aL + a] * sW[((l * Ww + w_) * P + p) * Qd + q];
    sT2[i] = acc;
  }
  __syncthreads();
  int n3 = Ww * KK;
  for (int i = threadIdx.x; i < n3; i += blockDim.x){
    int b = i % KK, w_ = i / KK;
    float acc = 0.f;
    for (int a = 0; a < aL; ++a)
      for (int q = 0; q < Qd; ++q)
        acc += sT2[(a * Ww + w_) * Qd + q] * A[((size_t)a * Qd + q) * KK + b];
    out[((size_t)r * Ww + w_) * KK + b] = acc;
  }
}

// Rnew[d,l,a] = sum B[a,q,b] R[r,w,b] w[l,w,p,q] m[d,p,r]; one WG per a.
__global__ __launch_bounds__(256) void k_renv(
    const float* __restrict__ B, const float* __restrict__ R,
    const float* __restrict__ w, const float* __restrict__ m, float* __restrict__ out,
    int aB, int Qd, int bR, int rm, int Ww, int lw, int P, int dm){
  int a = blockIdx.x;
  __shared__ float sB[512];    // (Qd, bR)
  __shared__ float sT1[4096];  // (q*rm + r)*Ww + w_
  __shared__ float sT2[4096];  // (r*lw + l)*P + p
  __shared__ float sW[4096];
  for (int i = threadIdx.x; i < Qd * bR; i += blockDim.x) sB[i] = B[(size_t)a * Qd * bR + i];
  for (int i = threadIdx.x; i < lw * Ww * P * Qd; i += blockDim.x) sW[i] = w[i];
  __syncthreads();
  for (int j = threadIdx.x; j < rm * Ww; j += blockDim.x){
    float acc[8];
    #pragma unroll
    for (int q = 0; q < 8; ++q) acc[q] = 0.f;
    const float* Rrow = R + (size_t)j * bR;     // j = r*Ww + w_
    for (int b = 0; b < bR; ++b){
      float Rv = Rrow[b];
      #pragma unroll
      for (int q = 0; q < 8; ++q) if (q < Qd) acc[q] += sB[q * bR + b] * Rv;
    }
    for (int q = 0; q < Qd; ++q) sT1[(size_t)q * rm * Ww + j] = acc[q];
  }
  __syncthreads();
  for (int i = threadIdx.x; i < rm * lw * P; i += blockDim.x){
    int p = i % P, t = i / P, l = t % lw, r = t / lw;
    float acc = 0.f;
    for (int q = 0; q < Qd; ++q)
      for (int w_ = 0; w_ < Ww; ++w_)
        acc += sT1[(q * rm + r) * Ww + w_] * sW[((l * Ww + w_) * P + p) * Qd + q];
    sT2[i] = acc;
  }
  __syncthreads();
  for (int i = threadIdx.x; i < dm * lw; i += blockDim.x){
    int l = i % lw, d = i / lw;
    float acc = 0.f;
    for (int r = 0; r < rm; ++r)
      for (int p = 0; p < P; ++p)
        acc += sT2[(r * lw + l) * P + p] * m[((size_t)d * P + p) * rm + r];
    out[((size_t)d * lw + l) * aB + a] = acc;
  }
}

struct FinalArgs { const float* t[10]; int dl[10]; int dr[10]; };

__global__ void k_final(FinalArgs fa, float* __restrict__ out){
  __shared__ float v0[64], v1[64];
  float* cur = v0; float* nxt = v1;
  if (threadIdx.x == 0) cur[0] = 1.0f;
  __syncthreads();
  for (int s = 0; s < 10; ++s){
    const float* T = fa.t[s]; int dl = fa.dl[s], dr = fa.dr[s];
    for (int j = threadIdx.x; j < dr; j += blockDim.x){
      float acc = 0.f;
      for (int i = 0; i < dl; ++i) acc += cur[i] * T[(size_t)i * dr + j];
      nxt[j] = acc;
    }
    __syncthreads();
    float* tmp = cur; cur = nxt; nxt = tmp;
  }
  if (threadIdx.x == 0) out[0] = cur[0];
}

static inline int imin2(int a, int b){ return a < b ? a : b; }

extern "C" void kernel_launch(void* const* d_in, const int* in_sizes, int n_in,
                              void* d_out, int out_size, void* d_ws, size_t ws_size,
                              hipStream_t stream){
  const float* tens = (const float*)d_in[0];
  const int*   samp = (const int*)d_in[1];
  float* out = (float*)d_out;
  float* ws  = (float*)d_ws;

  size_t off = 0;
  auto alloc = [&](size_t n){ float* p = ws + off; off += n; return p; };
  float* unit = alloc(64);
  float* mpo  = alloc((size_t)100 * 4096);
  float* bank[2][10];
  for (int b = 0; b < 2; ++b) for (int c = 0; c < 10; ++c) bank[b][c] = alloc(32768);
  float* renvB_[10]; float* lenvB_[10];
  for (int c = 0; c < 10; ++c) renvB_[c] = alloc(32768);
  for (int c = 0; c < 10; ++c) lenvB_[c] = alloc(32768);
  float* matbuf = alloc((size_t)512 * 512);
  float* carbuf[2] = { alloc(32768), alloc(32768) };
  float* optbuf = alloc(32768);

  k_init<<<dim3(1), dim3(1), 0, stream>>>(unit);
  k_mpo<<<dim3(100), dim3(256), 0, stream>>>(tens, samp, mpo);

  float* mps[10]; int mb[11];
  for (int c = 0; c < 10; ++c) mps[c] = unit;
  for (int c = 0; c <= 10; ++c) mb[c] = 1;
  int P = 1;

  int resL[10], resR[10];
  float* RENVP[10]; int renvDim[10];
  float* LENVP[10]; int lenvDim[10];

  for (int row = 0; row < 10; ++row){
    int Qd = (row == 9) ? 1 : 8;
    int Lm[10], Wm[10];
    for (int c = 0; c < 10; ++c){ Lm[c] = (c == 0) ? 1 : 8; Wm[c] = (c == 9) ? 1 : 8; }
    float** res_ = bank[row & 1];
    const float* mpoR = mpo + (size_t)row * 10 * 4096;

    // ---- init compressed MPS ----
    float* carry = unit; int kprev = 1; int cpar = 0;
    for (int c = 0; c < 10; ++c){
      int dmc = mb[c], rmc = mb[c + 1];
      int rows = kprev * Qd, cols = rmc * Wm[c];
      const float* wt = mpoR + (size_t)c * 4096;
      if (c == 9){
        k_init_theta<<<dim3(kprev), dim3(256), 0, stream>>>(carry, mps[c], wt, res_[9],
            kprev, dmc, Lm[c], P, rmc, Wm[c], Qd);
        resL[9] = kprev; resR[9] = cols;
      } else {
        k_init_theta<<<dim3(kprev), dim3(256), 0, stream>>>(carry, mps[c], wt, matbuf,
            kprev, dmc, Lm[c], P, rmc, Wm[c], Qd);
        int KK = imin2(64, imin2(rows, cols));
        k_panel<<<dim3(1), dim3(1024), 0, stream>>>(matbuf, res_[c], rows, KK, cols, 1, KK, 1);
        float* nc = carbuf[cpar]; cpar ^= 1;
        int tot = KK * cols;
        k_rmat<<<dim3((tot + 255) / 256), dim3(256), 0, stream>>>(res_[c], matbuf, nc,
            rows, KK, cols, cols, 1);
        resL[c] = kprev; resR[c] = KK;
        carry = nc; kprev = KK;
      }
    }

    // ---- build right envs ----
    RENVP[9] = unit; renvDim[9] = 1;
    for (int c = 8; c >= 0; --c){
      k_renv<<<dim3(resL[c + 1]), dim3(256), 0, stream>>>(res_[c + 1], RENVP[c + 1],
          mpoR + (size_t)(c + 1) * 4096, mps[c + 1], renvB_[c],
          resL[c + 1], Qd, resR[c + 1], mb[c + 2], Wm[c + 1], Lm[c + 1], P, mb[c + 1]);
      RENVP[c] = renvB_[c]; renvDim[c] = resL[c + 1];
    }

    for (int sweep = 0; sweep < 2; ++sweep){
      // ---- LR sweep ----
      LENVP[0] = unit; lenvDim[0] = 1;
      int aL = 1;
      for (int c = 0; c < 10; ++c){
        int bR = renvDim[c];
        const float* wt = mpoR + (size_t)c * 4096;
        float* outp = (c == 9) ? res_[9] : optbuf;
        k_optimal<<<dim3(aL), dim3(256), 0, stream>>>(mps[c], LENVP[c], wt, RENVP[c], outp,
            mb[c], P, mb[c + 1], Lm[c], aL, Wm[c], Qd, bR);
        if (c == 9){ resL[9] = aL; resR[9] = bR; break; }
        int rows = aL * Qd;
        int KK = imin2(64, imin2(rows, bR));
        k_panel<<<dim3(1), dim3(1024), 0, stream>>>(optbuf, res_[c], rows, KK, bR, 1, KK, 1);
        resL[c] = aL; resR[c] = KK;
        k_lenv<<<dim3(mb[c + 1]), dim3(256), 0, stream>>>(mps[c], LENVP[c], wt, res_[c],
            lenvB_[c + 1], mb[c], P, mb[c + 1], Lm[c], aL, Wm[c], Qd, KK);
        LENVP[c + 1] = lenvB_[c + 1]; lenvDim[c + 1] = KK;
        aL = KK;
      }
      // ---- RL sweep ----
      float* Rrun = unit; int bRr = 1;
      for (int c = 9; c >= 0; --c){
        RENVP[c] = Rrun; renvDim[c] = bRr;
        const float* wt = mpoR + (size_t)c * 4096;
        int aLc = lenvDim[c];
        float* outp = (c == 0) ? res_[0] : optbuf;
        k_optimal<<<dim3(aLc), dim3(256), 0, stream>>>(mps[c], LENVP[c], wt, Rrun, outp,
            mb[c], P, mb[c + 1], Lm[c], aLc, Wm[c], Qd, bRr);
        if (c == 0){ resL[0] = aLc; resR[0] = bRr; break; }
        int rowsT = Qd * bRr;
        int KK = imin2(64, imin2(rowsT, aLc));
        // panel on optimal^T: A_t(row=(q,b), col=a) at optbuf[col*rowsT + row]
        k_panel<<<dim3(1), dim3(1024), 0, stream>>>(optbuf, res_[c], rowsT, KK, 1, rowsT, 1, rowsT);
        resL[c] = KK; resR[c] = bRr;
        k_renv<<<dim3(KK), dim3(256), 0, stream>>>(res_[c], Rrun, wt, mps[c], renvB_[c - 1],
            KK, Qd, bRr, mb[c + 1], Wm[c], Lm[c], P, mb[c]);
        Rrun = renvB_[c - 1]; bRr = KK;
      }
    }

    // commit row result as new boundary
    for (int c = 0; c < 10; ++c){ mps[c] = res_[c]; mb[c + 1] = resR[c]; }
    mb[0] = 1;
    P = Qd;
  }

  FinalArgs fa;
  for (int c = 0; c < 10; ++c){ fa.t[c] = mps[c]; fa.dl[c] = resL[c]; fa.dr[c] = resR[c]; }
  k_final<<<dim3(1), dim3(64), 0, stream>>>(fa, out);
}

// Round 5
// 170482.898 us; speedup vs baseline: 2.7990x; 2.7990x over previous
//
#include <hip/hip_runtime.h>

// PEPS 10x10 boundary-MPS contraction, D=8, Dc=64, 2 sweeps, fp32.
// Host-orchestrated graph of ~1490 small kernels. All shapes are static
// (data-independent), so the schedule is identical every call (graph-safe).
//
// Conventions (matching the JAX reference):
//   mps site  m: (d, p, r)          row-major
//   mpo site  w: (l, w, p, q)       row-major  (p = up/in, q = down/out)
//   result    A: (a, q, b)          row-major
//   left env  L: (d, l, a)          row-major
//   right env R: (r, w, b)          row-major
// QR: Q_k = orthonormalization (MGS2) of the first KK columns; R = Q_k^T A.
// Gauge-invariance of the final scalar makes the QR basis convention free.
// Sweep neighbor C-updates in the reference are dead code and are elided.
//
// k_panel is templated on TT=ceil(M/64) so all per-thread arrays are
// compile-time-indexed (rule #20: runtime-indexed arrays -> scratch; this
// was the round-4 2.45x regression).

#define TINYF 1e-30f

__device__ __forceinline__ float wsum(float v){
  v += __shfl_xor(v, 1);  v += __shfl_xor(v, 2);  v += __shfl_xor(v, 4);
  v += __shfl_xor(v, 8);  v += __shfl_xor(v, 16); v += __shfl_xor(v, 32);
  return v;
}

__global__ void k_init(float* u){ u[0] = 1.0f; }

// Build all 100 MPO tensors: t = tensors[row,col,spin,:up,:dn,:lf,:rt] -> (l,w,p,q)
__global__ void k_mpo(const float* __restrict__ T, const int* __restrict__ spins,
                      float* __restrict__ mpo){
  int s = blockIdx.x; int row = s / 10, col = s % 10;
  int up = (row == 0) ? 1 : 8, dn = (row == 9) ? 1 : 8;
  int lf = (col == 0) ? 1 : 8, rt = (col == 9) ? 1 : 8;
  int spin = spins[s];
  const float* src = T + (size_t)(s * 2 + spin) * 4096; // strides: up=512, dn=64, lf=8, rt=1
  float* dst = mpo + (size_t)s * 4096;                  // (l, w, p, q) packed
  int n = lf * rt * up * dn;
  for (int i = threadIdx.x; i < n; i += blockDim.x){
    int q = i % dn, t1 = i / dn, p = t1 % up, t2 = t1 / up, w = t2 % rt, l = t2 / rt;
    dst[i] = src[p * 512 + q * 64 + l * 8 + w];
  }
}

// theta[k,q,r,w] = sum_{d,l,p} carry[k,d,l] m[d,p,r] w[l,w,p,q]
// out as matrix: out[(k*Qd+q)*(rm*Ww) + r*Ww + w_]
__global__ __launch_bounds__(256) void k_init_theta(
    const float* __restrict__ carry, const float* __restrict__ m,
    const float* __restrict__ w, float* __restrict__ out,
    int kdim, int dm, int lw, int P, int rm, int Ww, int Qd){
  int k = blockIdx.x;
  __shared__ float sC[512];    // (dm, lw)
  __shared__ float sT1[4096];  // (p*rm + r)*lw + l
  __shared__ float sW[4096];
  for (int i = threadIdx.x; i < dm * lw; i += blockDim.x) sC[i] = carry[(size_t)k * dm * lw + i];
  for (int i = threadIdx.x; i < lw * Ww * P * Qd; i += blockDim.x) sW[i] = w[i];
  __syncthreads();
  // stage 1: per-thread (p,r) pair, global operand hoisted per d
  for (int j = threadIdx.x; j < P * rm; j += blockDim.x){
    int r = j % rm, p = j / rm;
    float acc[8];
    #pragma unroll
    for (int l = 0; l < 8; ++l) acc[l] = 0.f;
    for (int d = 0; d < dm; ++d){
      float mv = m[((size_t)d * P + p) * rm + r];
      #pragma unroll
      for (int l = 0; l < 8; ++l) if (l < lw) acc[l] += mv * sC[d * lw + l];
    }
    float* dst = sT1 + (size_t)j * lw;
    for (int l = 0; l < lw; ++l) dst[l] = acc[l];
  }
  __syncthreads();
  int n2 = Qd * rm * Ww;
  int ldo = rm * Ww;
  for (int i = threadIdx.x; i < n2; i += blockDim.x){
    int w_ = i % Ww, t = i / Ww, r = t % rm, q = t / rm;
    float acc = 0.f;
    for (int l = 0; l < lw; ++l)
      for (int p = 0; p < P; ++p)
        acc += sT1[(p * rm + r) * lw + l] * sW[((l * Ww + w_) * P + p) * Qd + q];
    out[(size_t)(k * Qd + q) * ldo + r * Ww + w_] = acc;
  }
}

// Orthonormalize first KK columns of A (M rows), MGS2, register-resident.
// A(row,col) at A[row*ars + col*acs]; Q(row,col) at Q[row*qrs + col*qcs].
// 16 waves; wave w owns columns {w+16k}; column spread across 64 lanes
// (row = lane + 64t, t < TT, TT compile-time -> creg stays in VGPRs).
// Per pivot step only the pivot column goes through LDS (double-buffered),
// one __syncthreads per step. IO: direct coalesced when columns contiguous
// (ars==1); otherwise bounced through a padded LDS staging tile.
template<int TT>
__global__ __launch_bounds__(1024) void k_panel(
    const float* __restrict__ A, float* __restrict__ Q,
    int M, int KK, int ars, int acs, int qrs, int qcs){
  __shared__ float piv[2][512];   // pivot column, lane-major: [t*64 + lane]
  __shared__ float pnrm[2];       // pivot ||.||^2
  __shared__ float colnrm[64];    // final norms for store
  __shared__ float stg[64 * 65];  // staging tile, padded (+1 col)
  int wv = threadIdx.x >> 6, lane = threadIdx.x & 63;
  float creg[4][TT];
  #pragma unroll
  for (int k = 0; k < 4; ++k)
    #pragma unroll
    for (int t = 0; t < TT; ++t) creg[k][t] = 0.f;

  if (ars == 1){
    // columns contiguous in memory: direct coalesced load (lane = row)
    #pragma unroll
    for (int k = 0; k < 4; ++k){
      int c = wv + (k << 4);
      if (c < KK){
        const float* col = A + (size_t)c * acs;
        #pragma unroll
        for (int t = 0; t < TT; ++t){
          int r = lane + (t << 6);
          if (r < M) creg[k][t] = col[r];
        }
      }
    }
  } else {
    // row-major (acs==1): stage 64-row chunks through LDS, coalesced
    #pragma unroll
    for (int t = 0; t < TT; ++t){
      int r0 = t << 6;
      int nr = M - r0; if (nr > 64) nr = 64;
      __syncthreads();
      if (KK == 64){
        for (int i = threadIdx.x; i < (nr << 6); i += 1024){
          int rl = i >> 6, c = i & 63;
          stg[rl * 65 + c] = A[(size_t)(r0 + rl) * ars + c];
        }
      } else {
        for (int i = threadIdx.x; i < nr * KK; i += 1024){
          int rl = i / KK, c = i - rl * KK;
          stg[rl * 65 + c] = A[(size_t)(r0 + rl) * ars + c];
        }
      }
      __syncthreads();
      #pragma unroll
      for (int k = 0; k < 4; ++k){
        int c = wv + (k << 4);
        if (c < KK && lane < nr) creg[k][t] = stg[lane * 65 + c];
      }
    }
  }

  if (KK == 1){
    if (wv == 0){
      float s = 0.f;
      #pragma unroll
      for (int t = 0; t < TT; ++t) s += creg[0][t] * creg[0][t];
      s = wsum(s);
      if (lane == 0) colnrm[0] = s;
    }
    __syncthreads();
  } else {
    for (int pass = 0; pass < 2; ++pass){
      if (wv == 0){           // publish column 0 into buffer 0
        float s = 0.f;
        #pragma unroll
        for (int t = 0; t < TT; ++t) s += creg[0][t] * creg[0][t];
        s = wsum(s);
        #pragma unroll
        for (int t = 0; t < TT; ++t) piv[0][(t << 6) + lane] = creg[0][t];
        if (lane == 0){ pnrm[0] = s; if (pass == 1) colnrm[0] = s; }
      }
      __syncthreads();
      for (int j = 0; j < KK - 1; ++j){
        int buf = j & 1;
        float pv[TT];
        #pragma unroll
        for (int t = 0; t < TT; ++t) pv[t] = piv[buf][(t << 6) + lane];
        float invn = 1.0f / fmaxf(pnrm[buf], TINYF);
        #pragma unroll
        for (int k = 0; k < 4; ++k){
          int c = wv + (k << 4);
          if (c > j && c < KK){
            float d = 0.f;
            #pragma unroll
            for (int t = 0; t < TT; ++t) d += pv[t] * creg[k][t];
            d = wsum(d);
            float coef = d * invn;
            #pragma unroll
            for (int t = 0; t < TT; ++t) creg[k][t] -= coef * pv[t];
            if (c == j + 1){   // next pivot: publish updated column + norm
              float s = 0.f;
              #pragma unroll
              for (int t = 0; t < TT; ++t) s += creg[k][t] * creg[k][t];
              s = wsum(s);
              int nb = buf ^ 1;
              #pragma unroll
              for (int t = 0; t < TT; ++t) piv[nb][(t << 6) + lane] = creg[k][t];
              if (lane == 0){ pnrm[nb] = s; if (pass == 1) colnrm[j + 1] = s; }
            }
          }
        }
        __syncthreads();
      }
    }
  }

  // store Q = col * rsqrt(norm); colnrm visible via the last barrier
  float rs[4];
  #pragma unroll
  for (int k = 0; k < 4; ++k){
    int c = wv + (k << 4);
    rs[k] = (c < KK) ? rsqrtf(fmaxf(colnrm[c], TINYF)) : 0.f;
  }
  if (qrs == 1){
    // columns contiguous: direct coalesced store
    #pragma unroll
    for (int k = 0; k < 4; ++k){
      int c = wv + (k << 4);
      if (c < KK){
        float* col = Q + (size_t)c * qcs;
        #pragma unroll
        for (int t = 0; t < TT; ++t){
          int r = lane + (t << 6);
          if (r < M) col[r] = creg[k][t] * rs[k];
        }
      }
    }
  } else {
    // row-major (qcs==1): bounce through LDS, coalesced store
    #pragma unroll
    for (int t = 0; t < TT; ++t){
      int r0 = t << 6;
      int nr = M - r0; if (nr > 64) nr = 64;
      __syncthreads();
      #pragma unroll
      for (int k = 0; k < 4; ++k){
        int c = wv + (k << 4);
        if (c < KK && lane < nr) stg[lane * 65 + c] = creg[k][t] * rs[k];
      }
      __syncthreads();
      if (KK == 64){
        for (int i = threadIdx.x; i < (nr << 6); i += 1024){
          int rl = i >> 6, c = i & 63;
          Q[(size_t)(r0 + rl) * qrs + c] = stg[rl * 65 + c];
        }
      } else {
        for (int i = threadIdx.x; i < nr * KK; i += 1024){
          int rl = i / KK, c = i - rl * KK;
          Q[(size_t)(r0 + rl) * qrs + c] = stg[rl * 65 + c];
        }
      }
    }
  }
}

// R[c][n] = sum_m Q[m*KK + c] * A[m*ars + n*acs]   (R: KK x N, row-major)
__global__ __launch_bounds__(256) void k_rmat(
    const float* __restrict__ Q, const float* __restrict__ A, float* __restrict__ R,
    int M, int KK, int N, int ars, int acs){
  int idx = blockIdx.x * blockDim.x + threadIdx.x;
  if (idx >= KK * N) return;
  int n = idx % N, c = idx / N;
  float acc = 0.f;
  for (int mm = 0; mm < M; ++mm)
    acc += Q[(size_t)mm * KK + c] * A[(size_t)mm * ars + (size_t)n * acs];
  R[idx] = acc;
}

// optimal[a,q,b] = sum m[d,p,r] L[d,l,a] w[l,w,p,q] R[r,w,b]; one WG per a.
__global__ __launch_bounds__(256) void k_optimal(
    const float* __restrict__ m, const float* __restrict__ L,
    const float* __restrict__ w, const float* __restrict__ Renv, float* __restrict__ out,
    int dm, int P, int rm, int lw, int aL, int Ww, int Qd, int bR){
  int a = blockIdx.x;
  __shared__ float sL[512];    // (dm, lw)
  __shared__ float sT1[4096];  // (p*rm + r)*lw + l
  __shared__ float sT2[4096];  // (r*Ww + w_)*Qd + q
  __shared__ float sW[4096];
  for (int i = threadIdx.x; i < dm * lw; i += blockDim.x){
    int d = i / lw, l = i % lw;
    sL[i] = L[((size_t)d * lw + l) * aL + a];
  }
  for (int i = threadIdx.x; i < lw * Ww * P * Qd; i += blockDim.x) sW[i] = w[i];
  __syncthreads();
  for (int j = threadIdx.x; j < P * rm; j += blockDim.x){
    int r = j % rm, p = j / rm;
    float acc[8];
    #pragma unroll
    for (int l = 0; l < 8; ++l) acc[l] = 0.f;
    for (int d = 0; d < dm; ++d){
      float mv = m[((size_t)d * P + p) * rm + r];
      #pragma unroll
      for (int l = 0; l < 8; ++l) if (l < lw) acc[l] += mv * sL[d * lw + l];
    }
    float* dst = sT1 + (size_t)j * lw;
    for (int l = 0; l < lw; ++l) dst[l] = acc[l];
  }
  __syncthreads();
  for (int i = threadIdx.x; i < rm * Ww * Qd; i += blockDim.x){
    int q = i % Qd, t = i / Qd, w_ = t % Ww, r = t / Ww;
    float acc = 0.f;
    for (int l = 0; l < lw; ++l)
      for (int p = 0; p < P; ++p)
        acc += sT1[(p * rm + r) * lw + l] * sW[((l * Ww + w_) * P + p) * Qd + q];
    sT2[i] = acc;
  }
  __syncthreads();
  int n3 = Qd * bR;
  for (int i = threadIdx.x; i < n3; i += blockDim.x){
    int b = i % bR, q = i / bR;
    float acc = 0.f;
    for (int r = 0; r < rm; ++r)
      for (int w_ = 0; w_ < Ww; ++w_)
        acc += sT2[(r * Ww + w_) * Qd + q] * Renv[((size_t)r * Ww + w_) * bR + b];
    out[((size_t)a * Qd + q) * bR + b] = acc;
  }
}

// Lnew[r,w,b] = sum m[d,p,r] L[d,l,a] w[l,w,p,q] A[a,q,b]; one WG per r.
__global__ __launch_bounds__(256) void k_lenv(
    const float* __restrict__ m, const float* __restrict__ L,
    const float* __restrict__ w, const float* __restrict__ A, float* __restrict__ out,
    int dm, int P, int rm, int lw, int aL, int Ww, int Qd, int KK){
  int r = blockIdx.x;
  __shared__ float sM[512];    // (dm, P)
  __shared__ float sT1[4096];  // (p*lw + l)*aL + a
  __shared__ float sT2[4096];  // (a*Ww + w_)*Qd + q
  __shared__ float sW[4096];
  for (int i = threadIdx.x; i < dm * P; i += blockDim.x){
    int d = i / P, p = i % P;
    sM[i] = m[((size_t)d * P + p) * rm + r];
  }
  for (int i = threadIdx.x; i < lw * Ww * P * Qd; i += blockDim.x) sW[i] = w[i];
  __syncthreads();
  for (int j = threadIdx.x; j < lw * aL; j += blockDim.x){
    int a = j % aL, l = j / aL;
    float acc[8];
    #pragma unroll
    for (int p = 0; p < 8; ++p) acc[p] = 0.f;
    for (int d = 0; d < dm; ++d){
      float Lv = L[((size_t)d * lw + l) * aL + a];
      #pragma unroll
      for (int p = 0; p < 8; ++p) if (p < P) acc[p] += sM[d * P + p] * Lv;
    }
    for (int p = 0; p < P; ++p) sT1[(size_t)p * lw * aL + j] = acc[p];
  }
  __syncthreads();
  for (int i = threadIdx.x; i < aL * Ww * Qd; i += blockDim.x){
    int q = i % Qd, t = i / Qd, w_ = t % Ww, a = t / Ww;
    float acc = 0.f;
    for (int l = 0; l < lw; ++l)
      for (int p = 0; p < P; ++p)
        acc += sT1[(p * lw + l) * aL + a] * sW[((l * Ww + w_) * P + p) * Qd + q];
    sT2[i] = acc;
  }
  __syncthreads();
  int n3 = Ww * KK;
  for (int i = threadIdx.x; i < n3; i += blockDim.x){
    int b = i % KK, w_ = i / KK;
    float acc = 0.f;
    for (int a = 0; a < aL; ++a)
      for (int q = 0; q < Qd; ++q)
        acc += sT2[(a * Ww + w_) * Qd + q] * A[((size_t)a * Qd + q) * KK + b];
    out[((size_t)r * Ww + w_) * KK + b] = acc;
  }
}

// Rnew[d,l,a] = sum B[a,q,b] R[r,w,b] w[l,w,p,q] m[d,p,r]; one WG per a.
__global__ __launch_bounds__(256) void k_renv(
    const float* __restrict__ B, const float* __restrict__ R,
    const float* __restrict__ w, const float* __restrict__ m, float* __restrict__ out,
    int aB, int Qd, int bR, int rm, int Ww, int lw, int P, int dm){
  int a = blockIdx.x;
  __shared__ float sB[512];    // (Qd, bR)
  __shared__ float sT1[4096];  // (q*rm + r)*Ww + w_
  __shared__ float sT2[4096];  // (r*lw + l)*P + p
  __shared__ float sW[4096];
  for (int i = threadIdx.x; i < Qd * bR; i += blockDim.x) sB[i] = B[(size_t)a * Qd * bR + i];
  for (int i = threadIdx.x; i < lw * Ww * P * Qd; i += blockDim.x) sW[i] = w[i];
  __syncthreads();
  for (int j = threadIdx.x; j < rm * Ww; j += blockDim.x){
    float acc[8];
    #pragma unroll
    for (int q = 0; q < 8; ++q) acc[q] = 0.f;
    const float* Rrow = R + (size_t)j * bR;     // j = r*Ww + w_
    for (int b = 0; b < bR; ++b){
      float Rv = Rrow[b];
      #pragma unroll
      for (int q = 0; q < 8; ++q) if (q < Qd) acc[q] += sB[q * bR + b] * Rv;
    }
    for (int q = 0; q < Qd; ++q) sT1[(size_t)q * rm * Ww + j] = acc[q];
  }
  __syncthreads();
  for (int i = threadIdx.x; i < rm * lw * P; i += blockDim.x){
    int p = i % P, t = i / P, l = t % lw, r = t / lw;
    float acc = 0.f;
    for (int q = 0; q < Qd; ++q)
      for (int w_ = 0; w_ < Ww; ++w_)
        acc += sT1[(q * rm + r) * Ww + w_] * sW[((l * Ww + w_) * P + p) * Qd + q];
    sT2[i] = acc;
  }
  __syncthreads();
  for (int i = threadIdx.x; i < dm * lw; i += blockDim.x){
    int l = i % lw, d = i / lw;
    float acc = 0.f;
    for (int r = 0; r < rm; ++r)
      for (int p = 0; p < P; ++p)
        acc += sT2[(r * lw + l) * P + p] * m[((size_t)d * P + p) * rm + r];
    out[((size_t)d * lw + l) * aB + a] = acc;
  }
}

struct FinalArgs { const float* t[10]; int dl[10]; int dr[10]; };

__global__ void k_final(FinalArgs fa, float* __restrict__ out){
  __shared__ float v0[64], v1[64];
  float* cur = v0; float* nxt = v1;
  if (threadIdx.x == 0) cur[0] = 1.0f;
  __syncthreads();
  for (int s = 0; s < 10; ++s){
    const float* T = fa.t[s]; int dl = fa.dl[s], dr = fa.dr[s];
    for (int j = threadIdx.x; j < dr; j += blockDim.x){
      float acc = 0.f;
      for (int i = 0; i < dl; ++i) acc += cur[i] * T[(size_t)i * dr + j];
      nxt[j] = acc;
    }
    __syncthreads();
    float* tmp = cur; cur = nxt; nxt = tmp;
  }
  if (threadIdx.x == 0) out[0] = cur[0];
}

static inline int imin2(int a, int b){ return a < b ? a : b; }

static inline void launch_panel(const float* A, float* Q, int M, int KK,
                                int ars, int acs, int qrs, int qcs, hipStream_t st){
  int T = (M + 63) >> 6;   // 1..8 (M <= 512 always)
  switch (T){
    case 1: k_panel<1><<<dim3(1), dim3(1024), 0, st>>>(A, Q, M, KK, ars, acs, qrs, qcs); break;
    case 2: k_panel<2><<<dim3(1), dim3(1024), 0, st>>>(A, Q, M, KK, ars, acs, qrs, qcs); break;
    case 3: k_panel<3><<<dim3(1), dim3(1024), 0, st>>>(A, Q, M, KK, ars, acs, qrs, qcs); break;
    case 4: k_panel<4><<<dim3(1), dim3(1024), 0, st>>>(A, Q, M, KK, ars, acs, qrs, qcs); break;
    case 5: k_panel<5><<<dim3(1), dim3(1024), 0, st>>>(A, Q, M, KK, ars, acs, qrs, qcs); break;
    case 6: k_panel<6><<<dim3(1), dim3(1024), 0, st>>>(A, Q, M, KK, ars, acs, qrs, qcs); break;
    case 7: k_panel<7><<<dim3(1), dim3(1024), 0, st>>>(A, Q, M, KK, ars, acs, qrs, qcs); break;
    default: k_panel<8><<<dim3(1), dim3(1024), 0, st>>>(A, Q, M, KK, ars, acs, qrs, qcs); break;
  }
}

extern "C" void kernel_launch(void* const* d_in, const int* in_sizes, int n_in,
                              void* d_out, int out_size, void* d_ws, size_t ws_size,
                              hipStream_t stream){
  const float* tens = (const float*)d_in[0];
  const int*   samp = (const int*)d_in[1];
  float* out = (float*)d_out;
  float* ws  = (float*)d_ws;

  size_t off = 0;
  auto alloc = [&](size_t n){ float* p = ws + off; off += n; return p; };
  float* unit = alloc(64);
  float* mpo  = alloc((size_t)100 * 4096);
  float* bank[2][10];
  for (int b = 0; b < 2; ++b) for (int c = 0; c < 10; ++c) bank[b][c] = alloc(32768);
  float* renvB_[10]; float* lenvB_[10];
  for (int c = 0; c < 10; ++c) renvB_[c] = alloc(32768);
  for (int c = 0; c < 10; ++c) lenvB_[c] = alloc(32768);
  float* matbuf = alloc((size_t)512 * 512);
  float* carbuf[2] = { alloc(32768), alloc(32768) };
  float* optbuf = alloc(32768);

  k_init<<<dim3(1), dim3(1), 0, stream>>>(unit);
  k_mpo<<<dim3(100), dim3(256), 0, stream>>>(tens, samp, mpo);

  float* mps[10]; int mb[11];
  for (int c = 0; c < 10; ++c) mps[c] = unit;
  for (int c = 0; c <= 10; ++c) mb[c] = 1;
  int P = 1;

  int resL[10], resR[10];
  float* RENVP[10]; int renvDim[10];
  float* LENVP[10]; int lenvDim[10];

  for (int row = 0; row < 10; ++row){
    int Qd = (row == 9) ? 1 : 8;
    int Lm[10], Wm[10];
    for (int c = 0; c < 10; ++c){ Lm[c] = (c == 0) ? 1 : 8; Wm[c] = (c == 9) ? 1 : 8; }
    float** res_ = bank[row & 1];
    const float* mpoR = mpo + (size_t)row * 10 * 4096;

    // ---- init compressed MPS ----
    float* carry = unit; int kprev = 1; int cpar = 0;
    for (int c = 0; c < 10; ++c){
      int dmc = mb[c], rmc = mb[c + 1];
      int rows = kprev * Qd, cols = rmc * Wm[c];
      const float* wt = mpoR + (size_t)c * 4096;
      if (c == 9){
        k_init_theta<<<dim3(kprev), dim3(256), 0, stream>>>(carry, mps[c], wt, res_[9],
            kprev, dmc, Lm[c], P, rmc, Wm[c], Qd);
        resL[9] = kprev; resR[9] = cols;
      } else {
        k_init_theta<<<dim3(kprev), dim3(256), 0, stream>>>(carry, mps[c], wt, matbuf,
            kprev, dmc, Lm[c], P, rmc, Wm[c], Qd);
        int KK = imin2(64, imin2(rows, cols));
        launch_panel(matbuf, res_[c], rows, KK, cols, 1, KK, 1, stream);
        float* nc = carbuf[cpar]; cpar ^= 1;
        int tot = KK * cols;
        k_rmat<<<dim3((tot + 255) / 256), dim3(256), 0, stream>>>(res_[c], matbuf, nc,
            rows, KK, cols, cols, 1);
        resL[c] = kprev; resR[c] = KK;
        carry = nc; kprev = KK;
      }
    }

    // ---- build right envs ----
    RENVP[9] = unit; renvDim[9] = 1;
    for (int c = 8; c >= 0; --c){
      k_renv<<<dim3(resL[c + 1]), dim3(256), 0, stream>>>(res_[c + 1], RENVP[c + 1],
          mpoR + (size_t)(c + 1) * 4096, mps[c + 1], renvB_[c],
          resL[c + 1], Qd, resR[c + 1], mb[c + 2], Wm[c + 1], Lm[c + 1], P, mb[c + 1]);
      RENVP[c] = renvB_[c]; renvDim[c] = resL[c + 1];
    }

    for (int sweep = 0; sweep < 2; ++sweep){
      // ---- LR sweep ----
      LENVP[0] = unit; lenvDim[0] = 1;
      int aL = 1;
      for (int c = 0; c < 10; ++c){
        int bR = renvDim[c];
        const float* wt = mpoR + (size_t)c * 4096;
        float* outp = (c == 9) ? res_[9] : optbuf;
        k_optimal<<<dim3(aL), dim3(256), 0, stream>>>(mps[c], LENVP[c], wt, RENVP[c], outp,
            mb[c], P, mb[c + 1], Lm[c], aL, Wm[c], Qd, bR);
        if (c == 9){ resL[9] = aL; resR[9] = bR; break; }
        int rows = aL * Qd;
        int KK = imin2(64, imin2(rows, bR));
        launch_panel(optbuf, res_[c], rows, KK, bR, 1, KK, 1, stream);
        resL[c] = aL; resR[c] = KK;
        k_lenv<<<dim3(mb[c + 1]), dim3(256), 0, stream>>>(mps[c], LENVP[c], wt, res_[c],
            lenvB_[c + 1], mb[c], P, mb[c + 1], Lm[c], aL, Wm[c], Qd, KK);
        LENVP[c + 1] = lenvB_[c + 1]; lenvDim[c + 1] = KK;
        aL = KK;
      }
      // ---- RL sweep ----
      float* Rrun = unit; int bRr = 1;
      for (int c = 9; c >= 0; --c){
        RENVP[c] = Rrun; renvDim[c] = bRr;
        const float* wt = mpoR + (size_t)c * 4096;
        int aLc = lenvDim[c];
        float* outp = (c == 0) ? res_[0] : optbuf;
        k_optimal<<<dim3(aLc), dim3(256), 0, stream>>>(mps[c], LENVP[c], wt, Rrun, outp,
            mb[c], P, mb[c + 1], Lm[c], aLc, Wm[c], Qd, bRr);
        if (c == 0){ resL[0] = aLc; resR[0] = bRr; break; }
        int rowsT = Qd * bRr;
        int KK = imin2(64, imin2(rowsT, aLc));
        // panel on optimal^T: A_t(row=(q,b), col=a) at optbuf[col*rowsT + row]
        launch_panel(optbuf, res_[c], rowsT, KK, 1, rowsT, 1, rowsT, stream);
        resL[c] = KK; resR[c] = bRr;
        k_renv<<<dim3(KK), dim3(256), 0, stream>>>(res_[c], Rrun, wt, mps[c], renvB_[c - 1],
            KK, Qd, bRr, mb[c + 1], Wm[c], Lm[c], P, mb[c]);
        Rrun = renvB_[c - 1]; bRr = KK;
      }
    }

    // commit row result as new boundary
    for (int c = 0; c < 10; ++c){ mps[c] = res_[c]; mb[c + 1] = resR[c]; }
    mb[0] = 1;
    P = Qd;
  }

  FinalArgs fa;
  for (int c = 0; c < 10; ++c){ fa.t[c] = mps[c]; fa.dl[c] = resL[c]; fa.dr[c] = resR[c]; }
  k_final<<<dim3(1), dim3(64), 0, stream>>>(fa, out);
}

// Round 6
// 134185.938 us; speedup vs baseline: 3.5562x; 1.2705x over previous
//
#include <hip/hip_runtime.h>

// PEPS 10x10 boundary-MPS contraction, D=8, Dc=64, 2 sweeps, fp32.
// Host-orchestrated graph of ~1490 small kernels (static shapes, graph-safe).
//
// Conventions (matching the JAX reference):
//   mps site  m: (d, p, r)   mpo w: (l, w, p, q)   result A: (a, q, b)
//   left env  L: (d, l, a)   right env R: (r, w, b)
// QR: Q_k = MGS2 of first KK columns; R = Q_k^T A (basis-free, gauge-invariant).
// Sweep neighbor C-updates in the reference are dead code and are elided.
//
// Round-6: contraction kernels rebuilt for LDS bank-freedom + coalescing:
//  - W1 layout ((l*P+p)*Ww+w_)*Qd+q -> stage-2 reads 2x float4 (2-way, free)
//  - sT1/sT2 padded stride-9 rows (distinct banks across lanes)
//  - k_renv: R chunk-staged in LDS (was 256B-stride uncoalesced global),
//    B transposed to sBt[b*12+q] (aligned float4, conflict-free),
//    W2[l*516+(w_*Qd+q)*P+p] for p-vectored stage-2.

#define TINYF 1e-30f

__device__ __forceinline__ float wsum(float v){
  v += __shfl_xor(v, 1);  v += __shfl_xor(v, 2);  v += __shfl_xor(v, 4);
  v += __shfl_xor(v, 8);  v += __shfl_xor(v, 16); v += __shfl_xor(v, 32);
  return v;
}

__global__ void k_init(float* u){ u[0] = 1.0f; }

__global__ void k_mpo(const float* __restrict__ T, const int* __restrict__ spins,
                      float* __restrict__ mpo){
  int s = blockIdx.x; int row = s / 10, col = s % 10;
  int up = (row == 0) ? 1 : 8, dn = (row == 9) ? 1 : 8;
  int lf = (col == 0) ? 1 : 8, rt = (col == 9) ? 1 : 8;
  int spin = spins[s];
  const float* src = T + (size_t)(s * 2 + spin) * 4096; // strides: up=512, dn=64, lf=8, rt=1
  float* dst = mpo + (size_t)s * 4096;                  // (l, w, p, q) packed
  int n = lf * rt * up * dn;
  for (int i = threadIdx.x; i < n; i += blockDim.x){
    int q = i % dn, t1 = i / dn, p = t1 % up, t2 = t1 / up, w = t2 % rt, l = t2 / rt;
    dst[i] = src[p * 512 + q * 64 + l * 8 + w];
  }
}

// theta[k,q,r,w] = sum_{d,l,p} carry[k,d,l] m[d,p,r] w[l,w,p,q]; one WG per k.
__global__ __launch_bounds__(256) void k_init_theta(
    const float* __restrict__ carry, const float* __restrict__ m,
    const float* __restrict__ w, float* __restrict__ out,
    int kdim, int dm, int lw, int P, int rm, int Ww, int Qd){
  int k = blockIdx.x;
  __shared__ float sC[512];                       // (dm, lw)
  __shared__ __align__(16) float sW1[4096];       // ((l*P+p)*Ww + w_)*Qd + q
  __shared__ float sT1[4608];                     // (p*rm + r)*9 + l
  for (int i = threadIdx.x; i < dm * lw; i += blockDim.x) sC[i] = carry[(size_t)k * dm * lw + i];
  int wtot = lw * Ww * P * Qd;
  for (int i = threadIdx.x; i < wtot; i += blockDim.x){
    int q = i % Qd, t = i / Qd, p = t % P, t2 = t / P, w_ = t2 % Ww, l = t2 / Ww;
    sW1[((l * P + p) * Ww + w_) * Qd + q] = w[i];
  }
  __syncthreads();
  for (int j = threadIdx.x; j < P * rm; j += blockDim.x){
    int r = j % rm, p = j / rm;
    float acc[8];
    #pragma unroll
    for (int l = 0; l < 8; ++l) acc[l] = 0.f;
    for (int d = 0; d < dm; ++d){
      float mv = m[((size_t)d * P + p) * rm + r];
      #pragma unroll
      for (int l = 0; l < 8; ++l) if (l < lw) acc[l] += mv * sC[d * lw + l];
    }
    for (int l = 0; l < lw; ++l) sT1[j * 9 + l] = acc[l];
  }
  __syncthreads();
  int ldo = rm * Ww;
  if (Qd == 8){
    int slots = rm * Ww;
    for (int s = threadIdx.x; s < slots; s += blockDim.x){
      int w_ = s % Ww, r = s / Ww;
      float a0=0,a1=0,a2=0,a3=0,a4=0,a5=0,a6=0,a7=0;
      for (int l = 0; l < lw; ++l)
        for (int p = 0; p < P; ++p){
          float av = sT1[(p * rm + r) * 9 + l];
          const float4* w4 = (const float4*)&sW1[((l * P + p) * Ww + w_) * 8];
          float4 wa = w4[0], wb = w4[1];
          a0 += av * wa.x; a1 += av * wa.y; a2 += av * wa.z; a3 += av * wa.w;
          a4 += av * wb.x; a5 += av * wb.y; a6 += av * wb.z; a7 += av * wb.w;
        }
      float* o = out + (size_t)(k * 8) * ldo + r * Ww + w_;
      o[0*ldo]=a0; o[1*ldo]=a1; o[2*ldo]=a2; o[3*ldo]=a3;
      o[4*ldo]=a4; o[5*ldo]=a5; o[6*ldo]=a6; o[7*ldo]=a7;
    }
  } else {
    int n2 = Qd * rm * Ww;
    for (int i = threadIdx.x; i < n2; i += blockDim.x){
      int q = i % Qd, t = i / Qd, w_ = t % Ww, r = t / Ww;
      float acc = 0.f;
      for (int l = 0; l < lw; ++l)
        for (int p = 0; p < P; ++p)
          acc += sT1[(p * rm + r) * 9 + l] * sW1[((l * P + p) * Ww + w_) * Qd + q];
      out[(size_t)(k * Qd + q) * ldo + r * Ww + w_] = acc;
    }
  }
}

// MGS2 panel QR (unchanged from round 5 — register-resident, templated TT).
template<int TT>
__global__ __launch_bounds__(1024) void k_panel(
    const float* __restrict__ A, float* __restrict__ Q,
    int M, int KK, int ars, int acs, int qrs, int qcs){
  __shared__ float piv[2][512];
  __shared__ float pnrm[2];
  __shared__ float colnrm[64];
  __shared__ float stg[64 * 65];
  int wv = threadIdx.x >> 6, lane = threadIdx.x & 63;
  float creg[4][TT];
  #pragma unroll
  for (int k = 0; k < 4; ++k)
    #pragma unroll
    for (int t = 0; t < TT; ++t) creg[k][t] = 0.f;

  if (ars == 1){
    #pragma unroll
    for (int k = 0; k < 4; ++k){
      int c = wv + (k << 4);
      if (c < KK){
        const float* col = A + (size_t)c * acs;
        #pragma unroll
        for (int t = 0; t < TT; ++t){
          int r = lane + (t << 6);
          if (r < M) creg[k][t] = col[r];
        }
      }
    }
  } else {
    #pragma unroll
    for (int t = 0; t < TT; ++t){
      int r0 = t << 6;
      int nr = M - r0; if (nr > 64) nr = 64;
      __syncthreads();
      for (int i = threadIdx.x; i < nr * KK; i += 1024){
        int rl = i / KK, c = i - rl * KK;
        stg[rl * 65 + c] = A[(size_t)(r0 + rl) * ars + c];
      }
      __syncthreads();
      #pragma unroll
      for (int k = 0; k < 4; ++k){
        int c = wv + (k << 4);
        if (c < KK && lane < nr) creg[k][t] = stg[lane * 65 + c];
      }
    }
  }

  if (KK == 1){
    if (wv == 0){
      float s = 0.f;
      #pragma unroll
      for (int t = 0; t < TT; ++t) s += creg[0][t] * creg[0][t];
      s = wsum(s);
      if (lane == 0) colnrm[0] = s;
    }
    __syncthreads();
  } else {
    for (int pass = 0; pass < 2; ++pass){
      if (wv == 0){
        float s = 0.f;
        #pragma unroll
        for (int t = 0; t < TT; ++t) s += creg[0][t] * creg[0][t];
        s = wsum(s);
        #pragma unroll
        for (int t = 0; t < TT; ++t) piv[0][(t << 6) + lane] = creg[0][t];
        if (lane == 0){ pnrm[0] = s; if (pass == 1) colnrm[0] = s; }
      }
      __syncthreads();
      for (int j = 0; j < KK - 1; ++j){
        int buf = j & 1;
        float pv[TT];
        #pragma unroll
        for (int t = 0; t < TT; ++t) pv[t] = piv[buf][(t << 6) + lane];
        float invn = 1.0f / fmaxf(pnrm[buf], TINYF);
        #pragma unroll
        for (int k = 0; k < 4; ++k){
          int c = wv + (k << 4);
          if (c > j && c < KK){
            float d = 0.f;
            #pragma unroll
            for (int t = 0; t < TT; ++t) d += pv[t] * creg[k][t];
            d = wsum(d);
            float coef = d * invn;
            #pragma unroll
            for (int t = 0; t < TT; ++t) creg[k][t] -= coef * pv[t];
            if (c == j + 1){
              float s = 0.f;
              #pragma unroll
              for (int t = 0; t < TT; ++t) s += creg[k][t] * creg[k][t];
              s = wsum(s);
              int nb = buf ^ 1;
              #pragma unroll
              for (int t = 0; t < TT; ++t) piv[nb][(t << 6) + lane] = creg[k][t];
              if (lane == 0){ pnrm[nb] = s; if (pass == 1) colnrm[j + 1] = s; }
            }
          }
        }
        __syncthreads();
      }
    }
  }

  float rs[4];
  #pragma unroll
  for (int k = 0; k < 4; ++k){
    int c = wv + (k << 4);
    rs[k] = (c < KK) ? rsqrtf(fmaxf(colnrm[c], TINYF)) : 0.f;
  }
  if (qrs == 1){
    #pragma unroll
    for (int k = 0; k < 4; ++k){
      int c = wv + (k << 4);
      if (c < KK){
        float* col = Q + (size_t)c * qcs;
        #pragma unroll
        for (int t = 0; t < TT; ++t){
          int r = lane + (t << 6);
          if (r < M) col[r] = creg[k][t] * rs[k];
        }
      }
    }
  } else {
    #pragma unroll
    for (int t = 0; t < TT; ++t){
      int r0 = t << 6;
      int nr = M - r0; if (nr > 64) nr = 64;
      __syncthreads();
      #pragma unroll
      for (int k = 0; k < 4; ++k){
        int c = wv + (k << 4);
        if (c < KK && lane < nr) stg[lane * 65 + c] = creg[k][t] * rs[k];
      }
      __syncthreads();
      for (int i = threadIdx.x; i < nr * KK; i += 1024){
        int rl = i / KK, c = i - rl * KK;
        Q[(size_t)(r0 + rl) * qrs + c] = stg[rl * 65 + c];
      }
    }
  }
}

__global__ __launch_bounds__(256) void k_rmat(
    const float* __restrict__ Q, const float* __restrict__ A, float* __restrict__ R,
    int M, int KK, int N, int ars, int acs){
  int idx = blockIdx.x * blockDim.x + threadIdx.x;
  if (idx >= KK * N) return;
  int n = idx % N, c = idx / N;
  float acc = 0.f;
  for (int mm = 0; mm < M; ++mm)
    acc += Q[(size_t)mm * KK + c] * A[(size_t)mm * ars + (size_t)n * acs];
  R[idx] = acc;
}

// optimal[a,q,b] = sum m[d,p,r] L[d,l,a] w[l,w,p,q] R[r,w,b]; one WG per a.
__global__ __launch_bounds__(256) void k_optimal(
    const float* __restrict__ m, const float* __restrict__ L,
    const float* __restrict__ w, const float* __restrict__ Renv, float* __restrict__ out,
    int dm, int P, int rm, int lw, int aL, int Ww, int Qd, int bR){
  int a = blockIdx.x;
  __shared__ float sL[512];                       // (dm, lw)
  __shared__ __align__(16) float sW1[4096];       // ((l*P+p)*Ww + w_)*Qd + q
  __shared__ float sT1[4608];                     // (p*rm + r)*9 + l
  __shared__ float sT2[4608];                     // (r*Ww + w_)*9 + q
  for (int i = threadIdx.x; i < dm * lw; i += blockDim.x)
    sL[i] = L[(size_t)i * aL + a];
  int wtot = lw * Ww * P * Qd;
  for (int i = threadIdx.x; i < wtot; i += blockDim.x){
    int q = i % Qd, t = i / Qd, p = t % P, t2 = t / P, w_ = t2 % Ww, l = t2 / Ww;
    sW1[((l * P + p) * Ww + w_) * Qd + q] = w[i];
  }
  __syncthreads();
  for (int j = threadIdx.x; j < P * rm; j += blockDim.x){
    int r = j % rm, p = j / rm;
    float acc[8];
    #pragma unroll
    for (int l = 0; l < 8; ++l) acc[l] = 0.f;
    for (int d = 0; d < dm; ++d){
      float mv = m[((size_t)d * P + p) * rm + r];
      #pragma unroll
      for (int l = 0; l < 8; ++l) if (l < lw) acc[l] += mv * sL[d * lw + l];
    }
    for (int l = 0; l < lw; ++l) sT1[j * 9 + l] = acc[l];
  }
  __syncthreads();
  if (Qd == 8){
    int slots = rm * Ww;
    for (int s = threadIdx.x; s < slots; s += blockDim.x){
      int w_ = s % Ww, r = s / Ww;
      float a0=0,a1=0,a2=0,a3=0,a4=0,a5=0,a6=0,a7=0;
      for (int l = 0; l < lw; ++l)
        for (int p = 0; p < P; ++p){
          float av = sT1[(p * rm + r) * 9 + l];
          const float4* w4 = (const float4*)&sW1[((l * P + p) * Ww + w_) * 8];
          float4 wa = w4[0], wb = w4[1];
          a0 += av * wa.x; a1 += av * wa.y; a2 += av * wa.z; a3 += av * wa.w;
          a4 += av * wb.x; a5 += av * wb.y; a6 += av * wb.z; a7 += av * wb.w;
        }
      float* o = sT2 + s * 9;
      o[0]=a0; o[1]=a1; o[2]=a2; o[3]=a3; o[4]=a4; o[5]=a5; o[6]=a6; o[7]=a7;
    }
  } else {
    int n2 = Qd * rm * Ww;
    for (int i = threadIdx.x; i < n2; i += blockDim.x){
      int q = i % Qd, t = i / Qd, w_ = t % Ww, r = t / Ww;
      float acc = 0.f;
      for (int l = 0; l < lw; ++l)
        for (int p = 0; p < P; ++p)
          acc += sT1[(p * rm + r) * 9 + l] * sW1[((l * P + p) * Ww + w_) * Qd + q];
      sT2[(r * Ww + w_) * 9 + q] = acc;
    }
  }
  __syncthreads();
  int n3 = Qd * bR, nrw = rm * Ww;
  for (int i = threadIdx.x; i < n3; i += blockDim.x){
    int b = i % bR, q = i / bR;
    float acc = 0.f;
    for (int rw = 0; rw < nrw; ++rw)
      acc += sT2[rw * 9 + q] * Renv[(size_t)rw * bR + b];
    out[((size_t)a * Qd + q) * bR + b] = acc;
  }
}

// Lnew[r,w,b] = sum m[d,p,r] L[d,l,a] w[l,w,p,q] A[a,q,b]; one WG per r.
__global__ __launch_bounds__(256) void k_lenv(
    const float* __restrict__ m, const float* __restrict__ L,
    const float* __restrict__ w, const float* __restrict__ A, float* __restrict__ out,
    int dm, int P, int rm, int lw, int aL, int Ww, int Qd, int KK){
  int r = blockIdx.x;
  __shared__ float sM[512];                       // (dm, P)
  __shared__ __align__(16) float sW1[4096];       // ((l*P+p)*Ww + w_)*Qd + q
  __shared__ float sT1[4096];                     // (p*lw + l)*aL + a
  __shared__ float sT2[4608];                     // (a*Ww + w_)*9 + q
  for (int i = threadIdx.x; i < dm * P; i += blockDim.x){
    int d = i / P, p = i % P;
    sM[i] = m[((size_t)d * P + p) * rm + r];
  }
  int wtot = lw * Ww * P * Qd;
  for (int i = threadIdx.x; i < wtot; i += blockDim.x){
    int q = i % Qd, t = i / Qd, p = t % P, t2 = t / P, w_ = t2 % Ww, l = t2 / Ww;
    sW1[((l * P + p) * Ww + w_) * Qd + q] = w[i];
  }
  __syncthreads();
  for (int j = threadIdx.x; j < lw * aL; j += blockDim.x){
    int a = j % aL, l = j / aL;
    float acc[8];
    #pragma unroll
    for (int p = 0; p < 8; ++p) acc[p] = 0.f;
    for (int d = 0; d < dm; ++d){
      float Lv = L[((size_t)d * lw + l) * aL + a];
      #pragma unroll
      for (int p = 0; p < 8; ++p) if (p < P) acc[p] += sM[d * P + p] * Lv;
    }
    for (int p = 0; p < P; ++p) sT1[(size_t)p * lw * aL + j] = acc[p];
  }
  __syncthreads();
  if (Qd == 8){
    int slots = aL * Ww;
    for (int s = threadIdx.x; s < slots; s += blockDim.x){
      int w_ = s % Ww, aa = s / Ww;
      float a0=0,a1=0,a2=0,a3=0,a4=0,a5=0,a6=0,a7=0;
      for (int l = 0; l < lw; ++l)
        for (int p = 0; p < P; ++p){
          float av = sT1[(p * lw + l) * aL + aa];
          const float4* w4 = (const float4*)&sW1[((l * P + p) * Ww + w_) * 8];
          float4 wa = w4[0], wb = w4[1];
          a0 += av * wa.x; a1 += av * wa.y; a2 += av * wa.z; a3 += av * wa.w;
          a4 += av * wb.x; a5 += av * wb.y; a6 += av * wb.z; a7 += av * wb.w;
        }
      float* o = sT2 + s * 9;
      o[0]=a0; o[1]=a1; o[2]=a2; o[3]=a3; o[4]=a4; o[5]=a5; o[6]=a6; o[7]=a7;
    }
  } else {
    int n2 = Qd * aL * Ww;
    for (int i = threadIdx.x; i < n2; i += blockDim.x){
      int q = i % Qd, t = i / Qd, w_ = t % Ww, aa = t / Ww;
      float acc = 0.f;
      for (int l = 0; l < lw; ++l)
        for (int p = 0; p < P; ++p)
          acc += sT1[(p * lw + l) * aL + aa] * sW1[((l * P + p) * Ww + w_) * Qd + q];
      sT2[(aa * Ww + w_) * 9 + q] = acc;
    }
  }
  __syncthreads();
  int n3 = Ww * KK;
  for (int i = threadIdx.x; i < n3; i += blockDim.x){
    int b = i % KK, w_ = i / KK;
    float acc = 0.f;
    for (int aa = 0; aa < aL; ++aa)
      for (int q = 0; q < Qd; ++q)
        acc += sT2[(aa * Ww + w_) * 9 + q] * A[((size_t)aa * Qd + q) * KK + b];
    out[((size_t)r * Ww + w_) * KK + b] = acc;
  }
}

// Rnew[d,l,a] = sum B[a,q,b] R[r,w,b] w[l,w,p,q] m[d,p,r]; one WG per a.
__global__ __launch_bounds__(256) void k_renv(
    const float* __restrict__ B, const float* __restrict__ R,
    const float* __restrict__ w, const float* __restrict__ m, float* __restrict__ out,
    int aB, int Qd, int bR, int rm, int Ww, int lw, int P, int dm){
  int a = blockIdx.x;
  __shared__ __align__(16) float sBt[768];        // b*12 + q
  __shared__ __align__(16) float sW2[4128];       // l*(Ww*Qd*P+4) + (w_*Qd+q)*P + p
  __shared__ float sT1[4096];                     // q*(rm*Ww) + j
  __shared__ float sT2[4608];                     // (r*lw + l)*9 + p
  __shared__ float sR[128 * 65];                  // R chunk, row-padded
  int ls2 = Ww * Qd * P + 4;
  for (int i = threadIdx.x; i < Qd * bR; i += blockDim.x){
    int b = i % bR, q = i / bR;
    sBt[b * 12 + q] = B[((size_t)a * Qd + q) * bR + b];
  }
  int wtot = lw * Ww * P * Qd;
  for (int i = threadIdx.x; i < wtot; i += blockDim.x){
    int q = i % Qd, t = i / Qd, p = t % P, t2 = t / P, w_ = t2 % Ww, l = t2 / Ww;
    sW2[l * ls2 + (w_ * Qd + q) * P + p] = w[i];
  }
  int jmax = rm * Ww;
  // stage 1: chunk R through LDS (coalesced), compute sT1[q][j]
  for (int j0 = 0; j0 < jmax; j0 += 128){
    int nr = jmax - j0; if (nr > 128) nr = 128;
    __syncthreads();
    for (int i = threadIdx.x; i < nr * bR; i += blockDim.x){
      int jl = i / bR, b = i % bR;
      sR[jl * 65 + b] = R[(size_t)(j0 + jl) * bR + b];
    }
    __syncthreads();
    if (Qd == 8){
      for (int jl = threadIdx.x; jl < nr; jl += blockDim.x){
        float a0=0,a1=0,a2=0,a3=0,a4=0,a5=0,a6=0,a7=0;
        for (int b = 0; b < bR; ++b){
          float Rv = sR[jl * 65 + b];
          const float4* q4 = (const float4*)&sBt[b * 12];
          float4 qa = q4[0], qb = q4[1];
          a0 += qa.x * Rv; a1 += qa.y * Rv; a2 += qa.z * Rv; a3 += qa.w * Rv;
          a4 += qb.x * Rv; a5 += qb.y * Rv; a6 += qb.z * Rv; a7 += qb.w * Rv;
        }
        int j = j0 + jl;
        sT1[0*jmax + j]=a0; sT1[1*jmax + j]=a1; sT1[2*jmax + j]=a2; sT1[3*jmax + j]=a3;
        sT1[4*jmax + j]=a4; sT1[5*jmax + j]=a5; sT1[6*jmax + j]=a6; sT1[7*jmax + j]=a7;
      }
    } else {
      for (int i = threadIdx.x; i < nr * Qd; i += blockDim.x){
        int jl = i / Qd, q = i % Qd;
        float acc = 0.f;
        for (int b = 0; b < bR; ++b) acc += sBt[b * 12 + q] * sR[jl * 65 + b];
        sT1[(size_t)q * jmax + j0 + jl] = acc;
      }
    }
  }
  __syncthreads();
  // stage 2: sT2[r,l,p] = sum_{q,w_} sT1[q][r*Ww+w_] * w[l,w_,p,q]
  if (P == 8){
    int slots = rm * lw;
    for (int s = threadIdx.x; s < slots; s += blockDim.x){
      int l = s % lw, r = s / lw;
      float a0=0,a1=0,a2=0,a3=0,a4=0,a5=0,a6=0,a7=0;
      for (int q = 0; q < Qd; ++q)
        for (int w_ = 0; w_ < Ww; ++w_){
          float tv = sT1[q * jmax + r * Ww + w_];
          const float4* w4 = (const float4*)&sW2[l * ls2 + (w_ * Qd + q) * 8];
          float4 wa = w4[0], wb = w4[1];
          a0 += tv * wa.x; a1 += tv * wa.y; a2 += tv * wa.z; a3 += tv * wa.w;
          a4 += tv * wb.x; a5 += tv * wb.y; a6 += tv * wb.z; a7 += tv * wb.w;
        }
      float* o = sT2 + s * 9;
      o[0]=a0; o[1]=a1; o[2]=a2; o[3]=a3; o[4]=a4; o[5]=a5; o[6]=a6; o[7]=a7;
    }
  } else {
    int n2 = rm * lw * P;
    for (int i = threadIdx.x; i < n2; i += blockDim.x){
      int p = i % P, t = i / P, l = t % lw, r = t / lw;
      float acc = 0.f;
      for (int q = 0; q < Qd; ++q)
        for (int w_ = 0; w_ < Ww; ++w_)
          acc += sT1[q * jmax + r * Ww + w_] * sW2[l * ls2 + (w_ * Qd + q) * P + p];
      sT2[(r * lw + l) * 9 + p] = acc;
    }
  }
  __syncthreads();
  // stage 3: out[d,l,a] = sum_{r,p} sT2[r,l,p] * m[d,p,r]
  for (int i = threadIdx.x; i < dm * lw; i += blockDim.x){
    int l = i % lw, d = i / lw;
    float acc = 0.f;
    for (int r = 0; r < rm; ++r)
      for (int p = 0; p < P; ++p)
        acc += sT2[(r * lw + l) * 9 + p] * m[((size_t)d * P + p) * rm + r];
    out[((size_t)d * lw + l) * aB + a] = acc;
  }
}

struct FinalArgs { const float* t[10]; int dl[10]; int dr[10]; };

__global__ void k_final(FinalArgs fa, float* __restrict__ out){
  __shared__ float v0[64], v1[64];
  float* cur = v0; float* nxt = v1;
  if (threadIdx.x == 0) cur[0] = 1.0f;
  __syncthreads();
  for (int s = 0; s < 10; ++s){
    const float* T = fa.t[s]; int dl = fa.dl[s], dr = fa.dr[s];
    for (int j = threadIdx.x; j < dr; j += blockDim.x){
      float acc = 0.f;
      for (int i = 0; i < dl; ++i) acc += cur[i] * T[(size_t)i * dr + j];
      nxt[j] = acc;
    }
    __syncthreads();
    float* tmp = cur; cur = nxt; nxt = tmp;
  }
  if (threadIdx.x == 0) out[0] = cur[0];
}

static inline int imin2(int a, int b){ return a < b ? a : b; }

static inline void launch_panel(const float* A, float* Q, int M, int KK,
                                int ars, int acs, int qrs, int qcs, hipStream_t st){
  int T = (M + 63) >> 6;   // 1..8 (M <= 512 always)
  switch (T){
    case 1: k_panel<1><<<dim3(1), dim3(1024), 0, st>>>(A, Q, M, KK, ars, acs, qrs, qcs); break;
    case 2: k_panel<2><<<dim3(1), dim3(1024), 0, st>>>(A, Q, M, KK, ars, acs, qrs, qcs); break;
    case 3: k_panel<3><<<dim3(1), dim3(1024), 0, st>>>(A, Q, M, KK, ars, acs, qrs, qcs); break;
    case 4: k_panel<4><<<dim3(1), dim3(1024), 0, st>>>(A, Q, M, KK, ars, acs, qrs, qcs); break;
    case 5: k_panel<5><<<dim3(1), dim3(1024), 0, st>>>(A, Q, M, KK, ars, acs, qrs, qcs); break;
    case 6: k_panel<6><<<dim3(1), dim3(1024), 0, st>>>(A, Q, M, KK, ars, acs, qrs, qcs); break;
    case 7: k_panel<7><<<dim3(1), dim3(1024), 0, st>>>(A, Q, M, KK, ars, acs, qrs, qcs); break;
    default: k_panel<8><<<dim3(1), dim3(1024), 0, st>>>(A, Q, M, KK, ars, acs, qrs, qcs); break;
  }
}

extern "C" void kernel_launch(void* const* d_in, const int* in_sizes, int n_in,
                              void* d_out, int out_size, void* d_ws, size_t ws_size,
                              hipStream_t stream){
  const float* tens = (const float*)d_in[0];
  const int*   samp = (const int*)d_in[1];
  float* out = (float*)d_out;
  float* ws  = (float*)d_ws;

  size_t off = 0;
  auto alloc = [&](size_t n){ float* p = ws + off; off += n; return p; };
  float* unit = alloc(64);
  float* mpo  = alloc((size_t)100 * 4096);
  float* bank[2][10];
  for (int b = 0; b < 2; ++b) for (int c = 0; c < 10; ++c) bank[b][c] = alloc(32768);
  float* renvB_[10]; float* lenvB_[10];
  for (int c = 0; c < 10; ++c) renvB_[c] = alloc(32768);
  for (int c = 0; c < 10; ++c) lenvB_[c] = alloc(32768);
  float* matbuf = alloc((size_t)512 * 512);
  float* carbuf[2] = { alloc(32768), alloc(32768) };
  float* optbuf = alloc(32768);

  k_init<<<dim3(1), dim3(1), 0, stream>>>(unit);
  k_mpo<<<dim3(100), dim3(256), 0, stream>>>(tens, samp, mpo);

  float* mps[10]; int mb[11];
  for (int c = 0; c < 10; ++c) mps[c] = unit;
  for (int c = 0; c <= 10; ++c) mb[c] = 1;
  int P = 1;

  int resL[10], resR[10];
  float* RENVP[10]; int renvDim[10];
  float* LENVP[10]; int lenvDim[10];

  for (int row = 0; row < 10; ++row){
    int Qd = (row == 9) ? 1 : 8;
    int Lm[10], Wm[10];
    for (int c = 0; c < 10; ++c){ Lm[c] = (c == 0) ? 1 : 8; Wm[c] = (c == 9) ? 1 : 8; }
    float** res_ = bank[row & 1];
    const float* mpoR = mpo + (size_t)row * 10 * 4096;

    // ---- init compressed MPS ----
    float* carry = unit; int kprev = 1; int cpar = 0;
    for (int c = 0; c < 10; ++c){
      int dmc = mb[c], rmc = mb[c + 1];
      int rows = kprev * Qd, cols = rmc * Wm[c];
      const float* wt = mpoR + (size_t)c * 4096;
      if (c == 9){
        k_init_theta<<<dim3(kprev), dim3(256), 0, stream>>>(carry, mps[c], wt, res_[9],
            kprev, dmc, Lm[c], P, rmc, Wm[c], Qd);
        resL[9] = kprev; resR[9] = cols;
      } else {
        k_init_theta<<<dim3(kprev), dim3(256), 0, stream>>>(carry, mps[c], wt, matbuf,
            kprev, dmc, Lm[c], P, rmc, Wm[c], Qd);
        int KK = imin2(64, imin2(rows, cols));
        launch_panel(matbuf, res_[c], rows, KK, cols, 1, KK, 1, stream);
        float* nc = carbuf[cpar]; cpar ^= 1;
        int tot = KK * cols;
        k_rmat<<<dim3((tot + 255) / 256), dim3(256), 0, stream>>>(res_[c], matbuf, nc,
            rows, KK, cols, cols, 1);
        resL[c] = kprev; resR[c] = KK;
        carry = nc; kprev = KK;
      }
    }

    // ---- build right envs ----
    RENVP[9] = unit; renvDim[9] = 1;
    for (int c = 8; c >= 0; --c){
      k_renv<<<dim3(resL[c + 1]), dim3(256), 0, stream>>>(res_[c + 1], RENVP[c + 1],
          mpoR + (size_t)(c + 1) * 4096, mps[c + 1], renvB_[c],
          resL[c + 1], Qd, resR[c + 1], mb[c + 2], Wm[c + 1], Lm[c + 1], P, mb[c + 1]);
      RENVP[c] = renvB_[c]; renvDim[c] = resL[c + 1];
    }

    for (int sweep = 0; sweep < 2; ++sweep){
      // ---- LR sweep ----
      LENVP[0] = unit; lenvDim[0] = 1;
      int aL = 1;
      for (int c = 0; c < 10; ++c){
        int bR = renvDim[c];
        const float* wt = mpoR + (size_t)c * 4096;
        float* outp = (c == 9) ? res_[9] : optbuf;
        k_optimal<<<dim3(aL), dim3(256), 0, stream>>>(mps[c], LENVP[c], wt, RENVP[c], outp,
            mb[c], P, mb[c + 1], Lm[c], aL, Wm[c], Qd, bR);
        if (c == 9){ resL[9] = aL; resR[9] = bR; break; }
        int rows = aL * Qd;
        int KK = imin2(64, imin2(rows, bR));
        launch_panel(optbuf, res_[c], rows, KK, bR, 1, KK, 1, stream);
        resL[c] = aL; resR[c] = KK;
        k_lenv<<<dim3(mb[c + 1]), dim3(256), 0, stream>>>(mps[c], LENVP[c], wt, res_[c],
            lenvB_[c + 1], mb[c], P, mb[c + 1], Lm[c], aL, Wm[c], Qd, KK);
        LENVP[c + 1] = lenvB_[c + 1]; lenvDim[c + 1] = KK;
        aL = KK;
      }
      // ---- RL sweep ----
      float* Rrun = unit; int bRr = 1;
      for (int c = 9; c >= 0; --c){
        RENVP[c] = Rrun; renvDim[c] = bRr;
        const float* wt = mpoR + (size_t)c * 4096;
        int aLc = lenvDim[c];
        float* outp = (c == 0) ? res_[0] : optbuf;
        k_optimal<<<dim3(aLc), dim3(256), 0, stream>>>(mps[c], LENVP[c], wt, Rrun, outp,
            mb[c], P, mb[c + 1], Lm[c], aLc, Wm[c], Qd, bRr);
        if (c == 0){ resL[0] = aLc; resR[0] = bRr; break; }
        int rowsT = Qd * bRr;
        int KK = imin2(64, imin2(rowsT, aLc));
        // panel on optimal^T: A_t(row=(q,b), col=a) at optbuf[col*rowsT + row]
        launch_panel(optbuf, res_[c], rowsT, KK, 1, rowsT, 1, rowsT, stream);
        resL[c] = KK; resR[c] = bRr;
        k_renv<<<dim3(KK), dim3(256), 0, stream>>>(res_[c], Rrun, wt, mps[c], renvB_[c - 1],
            KK, Qd, bRr, mb[c + 1], Wm[c], Lm[c], P, mb[c]);
        Rrun = renvB_[c - 1]; bRr = KK;
      }
    }

    // commit row result as new boundary
    for (int c = 0; c < 10; ++c){ mps[c] = res_[c]; mb[c + 1] = resR[c]; }
    mb[0] = 1;
    P = Qd;
  }

  FinalArgs fa;
  for (int c = 0; c < 10; ++c){ fa.t[c] = mps[c]; fa.dl[c] = resL[c]; fa.dr[c] = resR[c]; }
  k_final<<<dim3(1), dim3(64), 0, stream>>>(fa, out);
}